// Round 15
// baseline (278.097 us; speedup 1.0000x reference)
//
#include <hip/hip_runtime.h>
#include <hip/hip_bf16.h>
#include <math.h>

#define BB 8
#define NN 4096
#define KNN 20
#define CH 64
#define SAMPLES (BB*NN*KNN)   /* 655360 */
#define EPSF 1e-5f
#define SLOPE 0.2f
#define MCOPY 32              /* mstats copies to spread atomic contention */

typedef float f32x4 __attribute__((ext_vector_type(4)));
typedef short bf16x8 __attribute__((ext_vector_type(8)));

/* decode order-preserving uint back to float */
__device__ __forceinline__ float key_decode(unsigned e) {
    return __uint_as_float((e & 0x80000000u) ? (e ^ 0x80000000u) : ~e);
}

/* rank-select flush: merge ovf[0..cnt) + inc[0..19] -> new exact top-20 in inc. */
__device__ __forceinline__ void rank_flush(unsigned long long* ovf,
                                           unsigned long long* inc,
                                           unsigned long long* scr,
                                           int& cnt, float& kthd, int lane) {
    while (cnt > 0) {
        int take = cnt < 44 ? cnt : 44;
        unsigned long long key;
        if (lane < take)      key = ovf[cnt - take + lane];
        else if (lane >= 44)  key = inc[lane - 44];
        else                  key = ~0ull;
        scr[lane] = key;
        __builtin_amdgcn_wave_barrier();
        int r = 0;
#pragma unroll
        for (int t = 0; t < 64; ++t) {
            unsigned long long kt = scr[t];       /* uniform addr -> broadcast */
            r += (kt < key) ? 1 : 0;
        }
        __builtin_amdgcn_wave_barrier();
        if (r < KNN) inc[r] = key;                /* padding ranks land >= 20 */
        __builtin_amdgcn_wave_barrier();
        kthd = key_decode((unsigned)(inc[KNN-1] >> 32));
        cnt -= take;
    }
}

/* ---------------- K0: per-batch: build pts4 + bitonic sort by x + zero stats --- */
__global__ __launch_bounds__(1024) void sort_kernel(const float* __restrict__ x,
        float4* __restrict__ pts4, float4* __restrict__ sp4, int* __restrict__ sidx,
        int* __restrict__ rankArr, double* __restrict__ zreg) {
#pragma clang fp contract(off)
    __shared__ unsigned long long S[NN];                     /* 32 KB */
    const int tid = threadIdx.x;
    const int b = blockIdx.x;
    if (b == 0 && tid < 992) zreg[tid] = 0.0;     /* mstats(864d) + stats2f(128d) */
    const float* xb = x + (size_t)b * 3 * NN;
    for (int i = tid; i < NN; i += 1024) {
        float mx = xb[i], my = xb[NN + i], mz = xb[2*NN + i];
        float sq = mx*mx; sq += my*my; sq += mz*mz;          /* ref summation order */
        pts4[(b << 12) + i] = make_float4(-2.0f*mx, -2.0f*my, -2.0f*mz, sq);
        unsigned uu = __float_as_uint(mx);
        unsigned e = uu ^ (((unsigned)((int)uu >> 31)) | 0x80000000u);
        S[i] = ((unsigned long long)e << 32) | (unsigned)i;
    }
    __syncthreads();
    for (int k = 2; k <= NN; k <<= 1) {
        for (int j = k >> 1; j > 0; j >>= 1) {
#pragma unroll
            for (int tt = 0; tt < 2; ++tt) {
                int t = tid + tt*1024;            /* 2048 pairs */
                int i = ((t & ~(j - 1)) << 1) | (t & (j - 1));
                int h = i | j;
                unsigned long long a = S[i], c = S[h];
                bool up = ((i & k) == 0);
                if ((a > c) == up) { S[i] = c; S[h] = a; }
            }
            __syncthreads();
        }
    }
    for (int s = tid; s < NN; s += 1024) {
        int oi = (int)(unsigned)(S[s] & 0xFFFFFFFFu);
        float mx = xb[oi], my = xb[NN + oi], mz = xb[2*NN + oi];  /* recompute: no RAW */
        float sq = mx*mx; sq += my*my; sq += mz*mz;
        sp4[(b << 12) + s] = make_float4(-2.0f*mx, -2.0f*my, -2.0f*mz, sq);
        sidx[(b << 12) + s] = oi;
        rankArr[(b << 12) + oi] = s;
    }
}

/* ---------------- K1: exact KNN — 2 sorted-adjacent queries per wave share one
   sweep (chunk loads, boundary checks, loop control amortize 2x). Per-query
   screens/OVF/INC/pruning stay independent -> identical neighbor sets. -------- */
__global__ __launch_bounds__(256) void knn_kernel(const float4* __restrict__ pts4,
        const float4* __restrict__ sp4, const int* __restrict__ sidx,
        int* __restrict__ idx_out, double* __restrict__ mstats) {
#pragma clang fp contract(off)
    __shared__ unsigned long long OVF[4][2][160];            /* 10 KB  */
    __shared__ unsigned long long INC[4][2][24];
    __shared__ unsigned long long SCR[4][64];
    __shared__ float MOM[4][27];
    const int tid = threadIdx.x;
    const int lane = tid & 63;
    const int wv = __builtin_amdgcn_readfirstlane(tid >> 6);
    const int s0 = (blockIdx.x * 4 + wv) * 2;                /* 2 sorted ranks */
    const int b = s0 >> 12;
    const int ss = s0 & (NN - 1);
    const float4* sb = sp4 + ((size_t)b << 12);
    const int* si = sidx + ((size_t)b << 12);
    unsigned long long* scr = &SCR[wv][0];

    float qx[2], qy[2], qz[2], sqn[2], kthd[2], thr[2], M[2];
    int cnt[2] = {0, 0};
#pragma unroll
    for (int i = 0; i < 2; ++i) {
        const float4 Qc = sb[ss + i];
        qx[i] = -0.5f*Qc.x; qy[i] = -0.5f*Qc.y; qz[i] = -0.5f*Qc.z;  /* exact */
        sqn[i] = Qc.w;
    }
    int c0 = ss - 31; c0 = c0 < 0 ? 0 : (c0 > NN-64 ? NN-64 : c0);   /* holds both */

    /* prefill: exact d for 64 nearest-in-x; rank-select per query */
    {
        const float4 P = sb[c0 + lane];
        const float mx = -0.5f*P.x, my = -0.5f*P.y, mz = -0.5f*P.z;
        const int oi = si[c0 + lane];
#pragma unroll
        for (int i = 0; i < 2; ++i) {
            float inner = qx[i]*mx; inner += qy[i]*my; inner += qz[i]*mz;
            const float d = (sqn[i] - 2.0f*inner) + P.w;     /* ref parenthesization */
            unsigned uu = __float_as_uint(d);
            unsigned e = uu ^ (((unsigned)((int)uu >> 31)) | 0x80000000u);
            unsigned long long key = ((unsigned long long)e << 32) | (unsigned)oi;
            scr[lane] = key;
            __builtin_amdgcn_wave_barrier();
            int r = 0;
#pragma unroll
            for (int t = 0; t < 64; ++t) {
                unsigned long long kt = scr[t];
                r += (kt < key) ? 1 : 0;
            }
            __builtin_amdgcn_wave_barrier();
            if (r < KNN) INC[wv][i][r] = key;
            __builtin_amdgcn_wave_barrier();
            kthd[i] = key_decode((unsigned)(INC[wv][i][KNN-1] >> 32));
            M[i] = 1e-3f*(fabsf(kthd[i]) + fabsf(sqn[i]) + 1.0f);
            thr[i] = (kthd[i] - sqn[i]) + M[i];
        }
    }

    int lo = c0, hi = c0 + 64;
    bool dl[2], dr[2];
    dl[0] = dl[1] = (lo == 0);
    dr[0] = dr[1] = (hi == NN);

    while (!dl[0] || !dl[1] || !dr[0] || !dr[1]) {
        if (!dl[0] || !dl[1]) {
            const float xb2 = -0.5f*sb[lo-1].x;              /* nearest unprocessed */
#pragma unroll
            for (int i = 0; i < 2; ++i) {
                if (!dl[i]) {
                    const float dx = qx[i] - xb2;
                    if (dx*dx > kthd[i] + M[i]) dl[i] = true;
                }
            }
            if (!dl[0] || !dl[1]) {
                const int st = (lo - 64) < 0 ? 0 : (lo - 64);
                const int sI = st + lane;
                const bool valid = sI < lo;
                const float4 P = sb[sI];                     /* shared chunk load */
                const int oi = si[sI];
#pragma unroll
                for (int i = 0; i < 2; ++i) {
                    if (dl[i]) continue;                     /* wave-uniform skip */
                    if (cnt[i] > 32) {
                        rank_flush(&OVF[wv][i][0], &INC[wv][i][0], scr, cnt[i], kthd[i], lane);
                        M[i] = 1e-3f*(fabsf(kthd[i]) + fabsf(sqn[i]) + 1.0f);
                        thr[i] = (kthd[i] - sqn[i]) + M[i];
                    }
                    const float sc = fmaf(P.x, qx[i], fmaf(P.y, qy[i], fmaf(P.z, qz[i], P.w)));
                    bool push = valid && (sc <= thr[i]);
                    unsigned long long mask = __ballot(push);
                    if (mask) {
                        if (push) {
                            const float mx = -0.5f*P.x, my = -0.5f*P.y, mz = -0.5f*P.z;
                            float inner = qx[i]*mx; inner += qy[i]*my; inner += qz[i]*mz;
                            const float d = (sqn[i] - 2.0f*inner) + P.w;
                            unsigned uu = __float_as_uint(d);
                            unsigned e = uu ^ (((unsigned)((int)uu >> 31)) | 0x80000000u);
                            unsigned long long key = ((unsigned long long)e << 32) | (unsigned)oi;
                            int ofs = (int)__popcll(mask & ((1ull << lane) - 1ull));
                            OVF[wv][i][cnt[i] + ofs] = key;
                        }
                        cnt[i] += (int)__popcll(mask);
                    }
                }
                lo = st;
                if (lo == 0) { dl[0] = dl[1] = true; }
            }
        }
        if (!dr[0] || !dr[1]) {
            const float xb2 = -0.5f*sb[hi].x;
#pragma unroll
            for (int i = 0; i < 2; ++i) {
                if (!dr[i]) {
                    const float dx = xb2 - qx[i];
                    if (dx*dx > kthd[i] + M[i]) dr[i] = true;
                }
            }
            if (!dr[0] || !dr[1]) {
                const int en = (hi + 64) > NN ? NN : (hi + 64);
                const int sI = hi + lane;
                const int sa = sI < NN-1 ? sI : NN-1;        /* clamp OOB lanes */
                const bool valid = sI < en;
                const float4 P = sb[sa];
                const int oi = si[sa];
#pragma unroll
                for (int i = 0; i < 2; ++i) {
                    if (dr[i]) continue;
                    if (cnt[i] > 32) {
                        rank_flush(&OVF[wv][i][0], &INC[wv][i][0], scr, cnt[i], kthd[i], lane);
                        M[i] = 1e-3f*(fabsf(kthd[i]) + fabsf(sqn[i]) + 1.0f);
                        thr[i] = (kthd[i] - sqn[i]) + M[i];
                    }
                    const float sc = fmaf(P.x, qx[i], fmaf(P.y, qy[i], fmaf(P.z, qz[i], P.w)));
                    bool push = valid && (sc <= thr[i]);
                    unsigned long long mask = __ballot(push);
                    if (mask) {
                        if (push) {
                            const float mx = -0.5f*P.x, my = -0.5f*P.y, mz = -0.5f*P.z;
                            float inner = qx[i]*mx; inner += qy[i]*my; inner += qz[i]*mz;
                            const float d = (sqn[i] - 2.0f*inner) + P.w;
                            unsigned uu = __float_as_uint(d);
                            unsigned e = uu ^ (((unsigned)((int)uu >> 31)) | 0x80000000u);
                            unsigned long long key = ((unsigned long long)e << 32) | (unsigned)oi;
                            int ofs = (int)__popcll(mask & ((1ull << lane) - 1ull));
                            OVF[wv][i][cnt[i] + ofs] = key;
                        }
                        cnt[i] += (int)__popcll(mask);
                    }
                }
                hi = en;
                if (hi == NN) { dr[0] = dr[1] = true; }
            }
        }
    }
#pragma unroll
    for (int i = 0; i < 2; ++i) {
        rank_flush(&OVF[wv][i][0], &INC[wv][i][0], scr, cnt[i], kthd[i], lane);
        if (lane < KNN)
            idx_out[(size_t)(s0 + i) * KNN + lane] =
                (int)(unsigned)(INC[wv][i][lane] & 0xFFFFFFFFull);
    }

    /* moments epilogue for both queries; lane 0 accumulates 27 values */
    float acc[27];
#pragma unroll
    for (int j = 0; j < 27; ++j) acc[j] = 0.f;
#pragma unroll
    for (int i = 0; i < 2; ++i) {
        float nx = 0.f, ny = 0.f, nz = 0.f, xx = 0.f, xy = 0.f, xz = 0.f,
              yy = 0.f, yz = 0.f, zz = 0.f;
        if (lane < KNN) {
            int nbr = (int)(unsigned)(INC[wv][i][lane] & 0xFFFFFFFFull);
            float4 pn = pts4[(b << 12) + nbr];
            nx = -0.5f*pn.x; ny = -0.5f*pn.y; nz = -0.5f*pn.z;
            xx = nx*nx; xy = nx*ny; xz = nx*nz; yy = ny*ny; yz = ny*nz; zz = nz*nz;
        }
#pragma unroll
        for (int off = 32; off > 0; off >>= 1) {
            nx += __shfl_xor(nx, off); ny += __shfl_xor(ny, off); nz += __shfl_xor(nz, off);
            xx += __shfl_xor(xx, off); xy += __shfl_xor(xy, off); xz += __shfl_xor(xz, off);
            yy += __shfl_xor(yy, off); yz += __shfl_xor(yz, off); zz += __shfl_xor(zz, off);
        }
        if (lane == 0) {
            acc[0] += nx;  acc[1] += ny;  acc[2] += nz;
            acc[3] += qx[i]; acc[4] += qy[i]; acc[5] += qz[i];
            acc[6] += xx;  acc[7] += xy;  acc[8] += xz;
            acc[9] += yy;  acc[10] += yz; acc[11] += zz;
            acc[12] += nx*qx[i]; acc[13] += nx*qy[i]; acc[14] += nx*qz[i];
            acc[15] += ny*qx[i]; acc[16] += ny*qy[i]; acc[17] += ny*qz[i];
            acc[18] += nz*qx[i]; acc[19] += nz*qy[i]; acc[20] += nz*qz[i];
            acc[21] += qx[i]*qx[i]; acc[22] += qx[i]*qy[i]; acc[23] += qx[i]*qz[i];
            acc[24] += qy[i]*qy[i]; acc[25] += qy[i]*qz[i]; acc[26] += qz[i]*qz[i];
        }
    }
    if (lane == 0) {
#pragma unroll
        for (int j = 0; j < 27; ++j) MOM[wv][j] = acc[j];
    }
    __syncthreads();
    if (tid < 27)
        atomicAdd(&mstats[(blockIdx.x & (MCOPY-1))*27 + tid],
                  (double)(MOM[0][tid] + MOM[1][tid] + MOM[2][tid] + MOM[3][tid]));
}

/* split fp32 -> bf16 hi (truncate) + bf16 lo (truncated remainder) */
__device__ __forceinline__ void bsplit(float g, short& hi, short& lo) {
    unsigned bits = __float_as_uint(g);
    unsigned hbits = bits & 0xFFFF0000u;
    float rem = g - __uint_as_float(hbits);
    hi = (short)(bits >> 16);
    lo = (short)(__float_as_uint(rem) >> 16);
}

/* ---------------- K5: main pass — shared-leftover-tile split-bf16 MFMA --------- */
__global__ __launch_bounds__(256) void main_kernel(const int* __restrict__ idxb,
        const int* __restrict__ rankArr, const float4* __restrict__ pts4,
        const double* __restrict__ ms, const float* __restrict__ W1,
        const float* __restrict__ gamma1, const float* __restrict__ beta1,
        const float* __restrict__ W2,
        float* __restrict__ maxbuf, float* __restrict__ stats2f) {
    __shared__ __align__(16) short Thi[4][32*72];
    __shared__ __align__(16) short Tlo[4][32*72];
    __shared__ float chs[128];
    __shared__ float ab1s[128];
    __shared__ double msd[27];
    const int tid = threadIdx.x;
    const int lane = tid & 63;
    const int wv = __builtin_amdgcn_readfirstlane(tid >> 6);
    const int l15 = lane & 15;
    const int quad = lane >> 4;
    if (tid < 128) chs[tid] = 0.f;
    if (tid < 27) {                                /* sum the 32 mstats copies */
        double t = 0.0;
        for (int c = 0; c < MCOPY; ++c) t += ms[c*27 + tid];
        msd[tid] = t;
    }
    __syncthreads();
    if (tid < 64) {                                /* inline fin1m (bn1 affine) */
        int c = tid;
        double wu[3], wvv[3];
#pragma unroll
        for (int i = 0; i < 3; ++i) {
            wu[i] = (double)W1[c*6 + i];
            wvv[i] = (double)W1[c*6 + 3 + i] - wu[i];
        }
        const double S = (double)SAMPLES;
        double mean = (wu[0]*msd[0] + wu[1]*msd[1] + wu[2]*msd[2]
                     + 20.0*(wvv[0]*msd[3] + wvv[1]*msd[4] + wvv[2]*msd[5])) / S;
        double qM1 = wu[0]*wu[0]*msd[6] + wu[1]*wu[1]*msd[9] + wu[2]*wu[2]*msd[11]
                   + 2.0*(wu[0]*wu[1]*msd[7] + wu[0]*wu[2]*msd[8] + wu[1]*wu[2]*msd[10]);
        double cross = 0.0;
#pragma unroll
        for (int i = 0; i < 3; ++i)
#pragma unroll
            for (int j = 0; j < 3; ++j)
                cross += wu[i] * msd[12 + i*3 + j] * wvv[j];
        double qpp = wvv[0]*wvv[0]*msd[21] + wvv[1]*wvv[1]*msd[24] + wvv[2]*wvv[2]*msd[26]
                   + 2.0*(wvv[0]*wvv[1]*msd[22] + wvv[0]*wvv[2]*msd[23] + wvv[1]*wvv[2]*msd[25]);
        double e2 = (qM1 + 2.0*cross + 20.0*qpp) / S;
        double var = e2 - mean*mean;
        float a = (float)((double)gamma1[c] / sqrt(var + (double)EPSF));
        ab1s[c] = a;
        ab1s[64 + c] = beta1[c] - a * (float)mean;
    }
    __syncthreads();

    bf16x8 whi[8], wlo[8];
#pragma unroll
    for (int t = 0; t < 4; ++t)
#pragma unroll
    for (int f = 0; f < 2; ++f) {
        const int o = 16*t + l15;
        const int c0 = 32*f + quad*8;
        const float4* wr = (const float4*)(W2 + o*64 + c0);
        float4 w0 = wr[0], w1 = wr[1];
        float vals[8] = {w0.x,w0.y,w0.z,w0.w,w1.x,w1.y,w1.z,w1.w};
        bf16x8 h, l;
#pragma unroll
        for (int j = 0; j < 8; ++j) { short hj, lj; bsplit(vals[j], hj, lj); h[j]=hj; l[j]=lj; }
        whi[t*2+f] = h; wlo[t*2+f] = l;
    }

    const float w10 = W1[lane*6+0], w11 = W1[lane*6+1], w12 = W1[lane*6+2];
    const float w13 = W1[lane*6+3], w14 = W1[lane*6+4], w15 = W1[lane*6+5];
    const float a1 = ab1s[lane], b1 = ab1s[64 + lane];
    float ssum[4] = {0.f,0.f,0.f,0.f}, ssq[4] = {0.f,0.f,0.f,0.f};
    float lm[4][4];                                /* deferred tile1 max [point][t] */
    short* thi = &Thi[wv][0];
    short* tlo = &Tlo[wv][0];

    const int pt0 = (blockIdx.x * 4 + wv) * 4;
    const int b = pt0 >> 12;
    const float4* pb = pts4 + ((size_t)b << 12);
    const int* rnk = rankArr + ((size_t)b << 12);

    for (int p = 0; p < 4; ++p) {
        const int pt = pt0 + p;
        const float4 pc = pb[pt & (NN - 1)];
        const float X = -0.5f*pc.x, Y = -0.5f*pc.y, Z = -0.5f*pc.z;
        const float vc = (w13 - w10)*X + (w14 - w11)*Y + (w15 - w12)*Z;
        const int srow = rnk[pt & (NN - 1)];       /* uniform scalar lookup */
        const int* irow = idxb + ((size_t)((b << 12) + srow)) * KNN;
#pragma unroll
        for (int k = 0; k < KNN; ++k) {
            float4 pn = pb[irow[k]];
            float nx = -0.5f*pn.x, ny = -0.5f*pn.y, nz = -0.5f*pn.z;
            float uc = w10*nx + w11*ny + w12*nz;
            float g = a1 * (uc + vc) + b1;
            g = fmaxf(g, SLOPE * g);
            short hj, lj; bsplit(g, hj, lj);
            const int row = (k < 16) ? k : (16 + p*4 + (k - 16));
            thi[row*72 + lane] = hj;
            tlo[row*72 + lane] = lj;
        }
        __builtin_amdgcn_wave_barrier();

        bf16x8 ah1[2], al1[2];
#pragma unroll
        for (int f = 0; f < 2; ++f) {
            const int co = 32*f + quad*8;
            ah1[f] = *(const bf16x8*)&thi[l15*72 + co];
            al1[f] = *(const bf16x8*)&tlo[l15*72 + co];
        }

        f32x4 acc1[4];
#pragma unroll
        for (int t = 0; t < 4; ++t) acc1[t] = (f32x4)0.f;
#pragma unroll
        for (int t = 0; t < 4; ++t) {
#pragma unroll
            for (int f = 0; f < 2; ++f) {
                acc1[t] = __builtin_amdgcn_mfma_f32_16x16x32_bf16(ah1[f], whi[t*2+f], acc1[t], 0,0,0);
                acc1[t] = __builtin_amdgcn_mfma_f32_16x16x32_bf16(al1[f], whi[t*2+f], acc1[t], 0,0,0);
                acc1[t] = __builtin_amdgcn_mfma_f32_16x16x32_bf16(ah1[f], wlo[t*2+f], acc1[t], 0,0,0);
            }
        }
        __builtin_amdgcn_wave_barrier();           /* tile1 reads done before next p */

        /* tile1 epilogue: reduce over rows k=0..15 (quads), defer the write */
#pragma unroll
        for (int t = 0; t < 4; ++t) {
            float m1 = fmaxf(fmaxf(acc1[t][0], acc1[t][1]), fmaxf(acc1[t][2], acc1[t][3]));
            float s1 = acc1[t][0] + acc1[t][1] + acc1[t][2] + acc1[t][3];
            float q1 = acc1[t][0]*acc1[t][0] + acc1[t][1]*acc1[t][1]
                     + acc1[t][2]*acc1[t][2] + acc1[t][3]*acc1[t][3];
            m1 = fmaxf(m1, __shfl_xor(m1, 16)); m1 = fmaxf(m1, __shfl_xor(m1, 32));
            s1 += __shfl_xor(s1, 16); s1 += __shfl_xor(s1, 32);
            q1 += __shfl_xor(q1, 16); q1 += __shfl_xor(q1, 32);
            lm[p][t] = m1;
            ssum[t] += s1; ssq[t] += q1;
        }
    }

    /* combined leftover tile: rows = p*4+(k-16), read once, 24 MFMA */
    {
        bf16x8 ah2[2], al2[2];
#pragma unroll
        for (int f = 0; f < 2; ++f) {
            const int co = 32*f + quad*8;
            ah2[f] = *(const bf16x8*)&thi[(16 + l15)*72 + co];
            al2[f] = *(const bf16x8*)&tlo[(16 + l15)*72 + co];
        }
        f32x4 accC[4];
#pragma unroll
        for (int t = 0; t < 4; ++t) accC[t] = (f32x4)0.f;
#pragma unroll
        for (int t = 0; t < 4; ++t) {
#pragma unroll
            for (int f = 0; f < 2; ++f) {
                accC[t] = __builtin_amdgcn_mfma_f32_16x16x32_bf16(ah2[f], whi[t*2+f], accC[t], 0,0,0);
                accC[t] = __builtin_amdgcn_mfma_f32_16x16x32_bf16(al2[f], whi[t*2+f], accC[t], 0,0,0);
                accC[t] = __builtin_amdgcn_mfma_f32_16x16x32_bf16(ah2[f], wlo[t*2+f], accC[t], 0,0,0);
            }
        }
        /* C row = quad*4+reg -> point = quad, k = 16+reg. */
#pragma unroll
        for (int t = 0; t < 4; ++t) {
            float cm = fmaxf(fmaxf(accC[t][0], accC[t][1]), fmaxf(accC[t][2], accC[t][3]));
            float cs = accC[t][0] + accC[t][1] + accC[t][2] + accC[t][3];
            float cq = accC[t][0]*accC[t][0] + accC[t][1]*accC[t][1]
                     + accC[t][2]*accC[t][2] + accC[t][3]*accC[t][3];
            float lmq = (quad == 0) ? lm[0][t] : (quad == 1) ? lm[1][t]
                      : (quad == 2) ? lm[2][t] : lm[3][t];
            maxbuf[((size_t)(pt0 + quad) << 6) + 16*t + l15] = fmaxf(lmq, cm);
            cs += __shfl_xor(cs, 16); cs += __shfl_xor(cs, 32);
            cq += __shfl_xor(cq, 16); cq += __shfl_xor(cq, 32);
            ssum[t] += cs; ssq[t] += cq;
        }
    }

    if (quad == 0) {
#pragma unroll
        for (int t = 0; t < 4; ++t) {
            atomicAdd(&chs[16*t + l15], ssum[t]);
            atomicAdd(&chs[64 + 16*t + l15], ssq[t]);
        }
    }
    __syncthreads();
    if (tid < 128)
        atomicAdd(&stats2f[(blockIdx.x & 1)*128 + tid], chs[tid]);
}

/* ---------------- K7: epilogue — fin2 inlined; transpose + bn2 + lrelu --------- */
__global__ __launch_bounds__(256) void out_kernel(const float* __restrict__ maxbuf,
        const float* __restrict__ s2f, const float* __restrict__ gamma2,
        const float* __restrict__ beta2, float* __restrict__ out) {
    __shared__ float t[64][65];
    __shared__ float ab2s[128];
    const int tid = threadIdx.x;
    if (tid < 64) {                                /* inline fin2 */
        int o = tid;
        double sum = (double)s2f[o] + (double)s2f[128 + o];
        double sq  = (double)s2f[64 + o] + (double)s2f[192 + o];
        double cnt = (double)SAMPLES;
        double mean = sum / cnt;
        double var  = sq / cnt - mean*mean;
        float a = (float)((double)gamma2[o] / sqrt(var + (double)EPSF));
        ab2s[o] = a;
        ab2s[64 + o] = beta2[o] - a * (float)mean;
    }
    const int b = blockIdx.x >> 6;
    const int n0 = (blockIdx.x & 63) << 6;
#pragma unroll
    for (int i = 0; i < 16; ++i) {
        int r = (tid >> 6) + i*4;
        int c = tid & 63;
        t[r][c] = maxbuf[(((size_t)((b << 12) + n0 + r)) << 6) + c];
    }
    __syncthreads();
#pragma unroll
    for (int i = 0; i < 16; ++i) {
        int o = (tid >> 6) + i*4;
        int nn = tid & 63;
        float a = ab2s[o], bb = ab2s[64 + o];
        float h = a * t[nn][o] + bb;
        out[(((size_t)(b*64 + o)) << 12) + n0 + nn] = h >= 0.f ? h : SLOPE*h;
    }
}

extern "C" void kernel_launch(void* const* d_in, const int* in_sizes, int n_in,
                              void* d_out, int out_size, void* d_ws, size_t ws_size,
                              hipStream_t stream) {
    const float* x      = (const float*)d_in[0];
    const float* W1     = (const float*)d_in[1];
    const float* gamma1 = (const float*)d_in[2];
    const float* beta1  = (const float*)d_in[3];
    const float* W2     = (const float*)d_in[4];
    const float* gamma2 = (const float*)d_in[5];
    const float* beta2  = (const float*)d_in[6];
    float* out = (float*)d_out;

    char* ws = (char*)d_ws;
    int*    idxb    = (int*)   (ws + 0);           /* 2,621,440 B (sorted order) */
    float4* pts4    = (float4*)(ws + 2621440);     /* 512 KB */
    float4* sp4     = (float4*)(ws + 3145728);     /* 512 KB sorted pts */
    int*    sidx    = (int*)   (ws + 3670016);     /* 128 KB sorted->orig */
    int*    rankArr = (int*)   (ws + 3801088);     /* 128 KB orig->sorted */
    float*  maxbuf  = (float*) (ws + 19398656);    /* 8,388,608 B, (b,n,o) */
    double* mstats  = (double*)(ws + 27787264);    /* 32x27 doubles = 6912 B */
    float*  stats2f = (float*) (ws + 27794176);    /* 2x128 floats = 1024 B */
    double* zreg    = (double*)(ws + 27787264);    /* zero region: 992 doubles */

    sort_kernel <<<8, 1024, 0, stream>>>(x, pts4, sp4, sidx, rankArr, zreg);
    knn_kernel  <<<4096, 256, 0, stream>>>(pts4, sp4, sidx, idxb, mstats);
    main_kernel <<<2048, 256, 0, stream>>>(idxb, rankArr, pts4, mstats, W1, gamma1,
                                           beta1, W2, maxbuf, stats2f);
    out_kernel  <<<512, 256, 0, stream>>>(maxbuf, stats2f, gamma2, beta2, out);
}